// Round 15
// baseline (115.069 us; speedup 1.0000x reference)
//
#include <hip/hip_runtime.h>
#include <hip/hip_bf16.h>

#define NB 64
#define NS 1024
#define DD 256
#define NT 36          // upper-triangular 8x8 tile count
#define THR 120.0f     // dist^2 below which exp(-dist) can matter
#define NBLK (NT * NB + 512)   // main grid: 2304 gram + 512 denomC blocks

typedef __attribute__((ext_vector_type(4))) float f32x4;
typedef __attribute__((ext_vector_type(8))) short bf16x8;
typedef unsigned long long u64;

__device__ __forceinline__ unsigned short f2bf(float x) {
  union { float f; unsigned int u; } c; c.f = x;
  unsigned int r = c.u + 0x7fffu + ((c.u >> 16) & 1u);
  return (unsigned short)(r >> 16);
}

// pack 4 f32 -> 4 fp8 e4m3 bytes (hardware cvt)
__device__ __forceinline__ unsigned int pk_fp8x4(float x, float y, float z, float w) {
  unsigned int v = 0;
#if __has_builtin(__builtin_amdgcn_cvt_pk_fp8_f32)
  v = __builtin_amdgcn_cvt_pk_fp8_f32(x, y, v, false);
  v = __builtin_amdgcn_cvt_pk_fp8_f32(z, w, v, true);
#else
  asm("v_cvt_pk_fp8_f32 %0, %1, %2" : "+v"(v) : "v"(x), "v"(y));
  asm("v_cvt_pk_fp8_f32 %0, %1, %2 op_sel:[0,0,1]" : "+v"(v) : "v"(z), "v"(w));
#endif
  return v;
}

// dbf3 layout (kg-major fp8 fragment blocks): block(b, kg, rt) = (b*8+kg)*64+rt,
// 512 BYTES each. Slot s (0..63) holds 8 fp8: row = rt*16 + (s&15),
// k = kg*32 + (s>>4)*8 + 0..7. fp8 e4m3 Gram precision is ample: G only
// reaches the output through the d2<THR gate and kd<=1.7e-5 terms.

// ---- prep (identical to R12): 4096 blocks x 128 thr, one 16-row tile each.
//      Coalesced 1KB f32 loads, exact-f32 sq, fp8 cvt, swizzled LDS transpose,
//      coalesced 512B fragment stores. XCD-matched to main's readers. ----
__global__ __launch_bounds__(128) void prep_kernel(const float* __restrict__ din,
                                                   unsigned char* __restrict__ dbf3,
                                                   float* __restrict__ sq,
                                                   int write_bf) {
  __shared__ unsigned char T[16][256];           // 4 KB fp8 tile
  const int px = (int)blockIdx.x;
  const int wid = (int)threadIdx.x >> 6;         // 0,1
  const int l = (int)threadIdx.x & 63;
  const int tb = (px & 7) * 512 + (px >> 3);     // tile task 0..4095
  const int b = tb >> 6, rt = tb & 63;
  const float4* src =
      reinterpret_cast<const float4*>(din + ((size_t)b * NS + rt * 16) * DD) + l;
  #pragma unroll
  for (int j = 0; j < 8; ++j) {
    const int ri = wid * 8 + j;                  // row within tile
    float4 v = src[ri * 64];                     // row stride 256 f = 64 float4
    float s = v.x * v.x + v.y * v.y + v.z * v.z + v.w * v.w;
    #pragma unroll
    for (int off = 32; off > 0; off >>= 1) s += __shfl_xor(s, off, 64);
    if (l == 0) sq[(size_t)b * NS + rt * 16 + ri] = s;
    if (write_bf) {
      const unsigned int w4 = pk_fp8x4(v.x, v.y, v.z, v.w);
      const int gp = l ^ ((ri & 15) << 2);
      *reinterpret_cast<unsigned int*>(&T[ri][gp * 4]) = w4;
    }
  }
  if (!write_bf) return;
  __syncthreads();
  unsigned char* dst = dbf3 + (((size_t)b * 8) * 64 + rt) * 512 + (size_t)l * 8;
  #pragma unroll
  for (int q = 0; q < 4; ++q) {
    const int kg = wid * 4 + q;
    const int gd = kg * 8 + (l >> 4) * 2;
    const int gp = gd ^ ((l & 15) << 2);
    const u64 frag = *reinterpret_cast<const u64*>(&T[l & 15][gp * 4]);
    *reinterpret_cast<u64*>(dst + (size_t)kg * 64 * 512) = frag;
  }
}

// ---- main: blocks [0,2304) gram jobs; [2304,2816) denomC partials; the LAST
// block to finish (device-scope counter) runs the final reduction in-place.
template <int MODE>
__global__ __launch_bounds__(256, 2) void main_kernel(
    const float* __restrict__ dvec, const unsigned char* __restrict__ dbf3,
    const float* __restrict__ sq, const float* __restrict__ S,
    const float* __restrict__ W, float* __restrict__ npart,
    float* __restrict__ dpart, float* __restrict__ cpart,
    unsigned int* __restrict__ counter, float* __restrict__ out) {
  const int tid = threadIdx.x;
  const int lane = tid & 63;
  const int wid = tid >> 6;
  const int orig = (int)blockIdx.x;
  __shared__ float redD[4], redC[4];
  __shared__ int lastFlag;

  if (orig >= NT * NB) {
    // ---- denomC partials: blk in [0,512), 256 thr x 2 float4 each ----
    const int blk = orig - NT * NB;
    const int base = blk * 256 + tid;
    float dsum = 0.f, csum = 0.f;
    #pragma unroll
    for (int rpt = 0; rpt < 2; ++rpt) {
      const int idx = base + rpt * 131072;
      float4 w = reinterpret_cast<const float4*>(W)[idx];
      float4 s4 = reinterpret_cast<const float4*>(S)[idx];
      const int e0 = idx << 2;
      const int r = e0 >> 10, c0 = e0 & 1023;
      float wv[4] = {w.x, w.y, w.z, w.w};
      float sv[4] = {s4.x, s4.y, s4.z, s4.w};
      #pragma unroll
      for (int i = 0; i < 4; ++i) {
        const bool dg = (c0 + i) == r;
        const float a = wv[i] - (dg ? 1.0f : 0.0f);
        dsum = fmaf(a, a, dsum);
        const float bq = dg ? (1.0f - sv[i]) : sv[i];
        csum = fmaf(wv[i] * bq, bq, csum);   // W binary: W^2 == W
      }
    }
    #pragma unroll
    for (int off = 32; off > 0; off >>= 1) {
      dsum += __shfl_xor(dsum, off, 64);
      csum += __shfl_xor(csum, off, 64);
    }
    if (lane == 0) { redD[wid] = dsum; redC[wid] = csum; }
    __syncthreads();
    if (tid == 0) {
      dpart[blk] = redD[0] + redD[1] + redD[2] + redD[3];
      cpart[blk] = redC[0] + redC[1] + redC[2] + redC[3];
    }
  } else {
    const int wr = wid >> 1;
    const int wc = wid & 1;
    // XCD-chunked bijective swizzle (2304 = 8 * 288): XCD k gets bids
    // [288k, 288k+288) -> b in [8k, 8k+8) = the batches its L2 holds.
    const int bid = (orig & 7) * (NT * NB / 8) + (orig >> 3);
    const int t = bid % NT;
    const int b = bid / NT;
    int u = t, ti = 0;
    while (u >= 8 - ti) { u -= 8 - ti; ++ti; }
    const int tj = ti + u;
    const int brow = ti * 128;
    const int bcol = tj * 128;

    const int rtA0 = ti * 8 + wr * 4;   // A row-tiles (16 rows each)
    const int rtB0 = tj * 8 + wc * 4;   // B row-tiles (Gram columns)

    f32x4 acc[4][4];
    #pragma unroll
    for (int m = 0; m < 4; ++m)
      #pragma unroll
      for (int n = 0; n < 4; ++n) acc[m][n] = f32x4{0.f, 0.f, 0.f, 0.f};

    if (MODE == 0) {
      const unsigned char* pa =
          dbf3 + (((size_t)b * 8) * 64 + rtA0) * 512 + (size_t)lane * 8;
      const unsigned char* pb =
          dbf3 + (((size_t)b * 8) * 64 + rtB0) * 512 + (size_t)lane * 8;
      u64 af[4], bf[4], nf[4];
      #pragma unroll
      for (int m = 0; m < 4; ++m)
        af[m] = *reinterpret_cast<const u64*>(pa + m * 512);
      #pragma unroll
      for (int n = 0; n < 4; ++n)
        bf[n] = *reinterpret_cast<const u64*>(pb + n * 512);
      #pragma unroll
      for (int kg = 0; kg < 8; ++kg) {
        if (kg < 7) {
          #pragma unroll
          for (int m = 0; m < 4; ++m)
            nf[m] = *reinterpret_cast<const u64*>(pa + 32768 + m * 512);
        }
        #pragma unroll
        for (int n = 0; n < 4; ++n) {
          #pragma unroll
          for (int m = 0; m < 4; ++m)
            acc[m][n] = __builtin_amdgcn_mfma_f32_16x16x32_fp8_fp8(
                (long)af[m], (long)bf[n], acc[m][n], 0, 0, 0);
          if (kg < 7)
            bf[n] = *reinterpret_cast<const u64*>(pb + 32768 + n * 512);
        }
        if (kg < 7) {
          #pragma unroll
          for (int m = 0; m < 4; ++m) af[m] = nf[m];
          pa += 32768; pb += 32768;
        }
      }
    } else {
      const float* pbase = dvec + (size_t)b * NS * DD + (lane >> 4) * 8;
      #pragma unroll
      for (int kg = 0; kg < 8; ++kg) {
        bf16x8 af[4], bf[4];
        #pragma unroll
        for (int m = 0; m < 4; ++m) {
          const float* p = pbase + (size_t)((rtA0 + m) * 16 + (lane & 15)) * DD + kg * 32;
          float4 v0 = reinterpret_cast<const float4*>(p)[0];
          float4 v1 = reinterpret_cast<const float4*>(p)[1];
          af[m][0] = (short)f2bf(v0.x); af[m][1] = (short)f2bf(v0.y);
          af[m][2] = (short)f2bf(v0.z); af[m][3] = (short)f2bf(v0.w);
          af[m][4] = (short)f2bf(v1.x); af[m][5] = (short)f2bf(v1.y);
          af[m][6] = (short)f2bf(v1.z); af[m][7] = (short)f2bf(v1.w);
        }
        #pragma unroll
        for (int n = 0; n < 4; ++n) {
          const float* p = pbase + (size_t)((rtB0 + n) * 16 + (lane & 15)) * DD + kg * 32;
          float4 v0 = reinterpret_cast<const float4*>(p)[0];
          float4 v1 = reinterpret_cast<const float4*>(p)[1];
          bf[n][0] = (short)f2bf(v0.x); bf[n][1] = (short)f2bf(v0.y);
          bf[n][2] = (short)f2bf(v0.z); bf[n][3] = (short)f2bf(v0.w);
          bf[n][4] = (short)f2bf(v1.x); bf[n][5] = (short)f2bf(v1.y);
          bf[n][6] = (short)f2bf(v1.z); bf[n][7] = (short)f2bf(v1.w);
        }
        #pragma unroll
        for (int m = 0; m < 4; ++m)
          #pragma unroll
          for (int n = 0; n < 4; ++n)
            acc[m][n] = __builtin_amdgcn_mfma_f32_16x16x32_bf16(af[m], bf[n], acc[m][n], 0, 0, 0);
      }
    }

    // epilogue: branch-free d2 min scan; rare kd path under one ballot.
    const float* sqb = sq + (size_t)b * NS;
    const int hi = lane >> 4, lo = lane & 15;
    float sqc[4];
    #pragma unroll
    for (int n = 0; n < 4; ++n) sqc[n] = sqb[bcol + wc * 64 + n * 16 + lo];
    float dmin = 1e30f;
    #pragma unroll
    for (int m = 0; m < 4; ++m) {
      #pragma unroll
      for (int j = 0; j < 4; ++j) {
        const int r = brow + wr * 64 + m * 16 + hi * 4 + j;
        const float sqr = sqb[r];
        #pragma unroll
        for (int n = 0; n < 4; ++n) {
          const int c = bcol + wc * 64 + n * 16 + lo;
          const float d2 = fmaxf(sqr + sqc[n] - 2.0f * acc[m][n][j], 0.0f);
          dmin = fminf(dmin, (r < c) ? d2 : 1e30f);
        }
      }
    }
    float wsum = 0.f;
    if (__any(dmin < THR)) {
      float lsum = 0.f;
      #pragma unroll
      for (int m = 0; m < 4; ++m) {
        #pragma unroll
        for (int j = 0; j < 4; ++j) {
          const int r = brow + wr * 64 + m * 16 + hi * 4 + j;
          const float sqr = sqb[r];
          #pragma unroll
          for (int n = 0; n < 4; ++n) {
            const int c = bcol + wc * 64 + n * 16 + lo;
            const float d2 = fmaxf(sqr + sqc[n] - 2.0f * acc[m][n][j], 0.0f);
            if ((r < c) && (d2 < THR)) {
              const float kd = __expf(-sqrtf(d2));
              const float wrc = W[(size_t)r * NS + c];
              const float wcr = W[(size_t)c * NS + r];
              const float src_ = S[(size_t)r * NS + c];
              const float scr = S[(size_t)c * NS + r];
              lsum = fmaf(kd, kd * (wrc + wcr) - 2.0f * fmaf(wrc, src_, wcr * scr), lsum);
            }
          }
        }
      }
      #pragma unroll
      for (int off = 32; off > 0; off >>= 1) lsum += __shfl_xor(lsum, off, 64);
      wsum = lsum;
    }
    // unconditional per-(block,wave) partial (poison-safe, no atomics)
    if (lane == 0) npart[(size_t)bid * 4 + wid] = wsum;
  }

  // ---- last-block completion: the final block to arrive reduces everything.
  __syncthreads();
  if (tid == 0) {
    __threadfence();                             // publish this block's writes
    const unsigned int old = atomicAdd(counter, 1u);
    lastFlag = (old == NBLK - 1) ? 1 : 0;
  }
  __syncthreads();
  if (lastFlag) {
    __threadfence();                             // acquire all blocks' writes
    if (tid < 64) {
      float dsum = 0.f, csum = 0.f;
      #pragma unroll
      for (int j = 0; j < 8; ++j) {
        dsum += dpart[tid + 64 * j];
        csum += cpart[tid + 64 * j];
      }
      #pragma unroll
      for (int off = 32; off > 0; off >>= 1) {
        dsum += __shfl_xor(dsum, off, 64);
        csum += __shfl_xor(csum, off, 64);
      }
      // lane b: reduce its batch's 36 tiles x 4 waves = 144 contiguous floats
      float nb = 0.f;
      const f32x4* np = reinterpret_cast<const f32x4*>(npart + (size_t)tid * 144);
      #pragma unroll
      for (int j = 0; j < 36; ++j) {
        f32x4 v = np[j];
        nb += v[0] + v[1] + v[2] + v[3];
      }
      float v = 2.0f * sqrtf(csum + nb);
      #pragma unroll
      for (int off = 32; off > 0; off >>= 1) v += __shfl_xor(v, off, 64);
      if (tid == 0) out[0] = v / sqrtf(dsum);
    }
  }
}

extern "C" void kernel_launch(void* const* d_in, const int* in_sizes, int n_in,
                              void* d_out, int out_size, void* d_ws, size_t ws_size,
                              hipStream_t stream) {
  const float* dvec = (const float*)d_in[0];
  const float* S = (const float*)d_in[1];
  const float* W = (const float*)d_in[2];
  float* out = (float*)d_out;

  const size_t bf_bytes = (size_t)NB * NS * DD;                           // 16 MiB fp8
  const size_t sq_bytes = (size_t)NB * NS * sizeof(float);                // 256 KiB
  const size_t small_bytes = sq_bytes + (9216 + 512 + 512 + 1) * sizeof(float);
  const bool full = ws_size >= bf_bytes + small_bytes;

  unsigned char* dbf3;
  float* sqp;
  if (full) {
    dbf3 = (unsigned char*)d_ws;
    sqp = (float*)((char*)d_ws + bf_bytes);
  } else {
    dbf3 = nullptr;
    sqp = (float*)d_ws;
  }
  float* npart = sqp + (size_t)NB * NS;    // 9216 floats (2304 jobs x 4 waves)
  float* dpart = npart + 9216;             // 512
  float* cpart = dpart + 512;              // 512
  unsigned int* counter = (unsigned int*)(cpart + 512);

  hipMemsetAsync(counter, 0, sizeof(unsigned int), stream);
  prep_kernel<<<4096, 128, 0, stream>>>(dvec, dbf3, sqp, full ? 1 : 0);
  if (full)
    main_kernel<0><<<NBLK, 256, 0, stream>>>(dvec, dbf3, sqp, S, W,
                                             npart, dpart, cpart, counter, out);
  else
    main_kernel<1><<<NBLK, 256, 0, stream>>>(dvec, dbf3, sqp, S, W,
                                             npart, dpart, cpart, counter, out);
}

// Round 16
// 42.131 us; speedup vs baseline: 2.7312x; 2.7312x over previous
//
#include <hip/hip_runtime.h>
#include <hip/hip_bf16.h>

#define NB 64
#define NS 1024
#define DD 256
#define NT 36          // upper-triangular 8x8 tile count
#define THR 120.0f     // dist^2 below which exp(-dist) can matter

typedef __attribute__((ext_vector_type(4))) float f32x4;
typedef __attribute__((ext_vector_type(8))) short bf16x8;
typedef unsigned long long u64;

__device__ __forceinline__ unsigned short f2bf(float x) {
  union { float f; unsigned int u; } c; c.f = x;
  unsigned int r = c.u + 0x7fffu + ((c.u >> 16) & 1u);
  return (unsigned short)(r >> 16);
}

// pack 4 f32 -> 4 fp8 e4m3 bytes (hardware cvt)
__device__ __forceinline__ unsigned int pk_fp8x4(float x, float y, float z, float w) {
  unsigned int v = 0;
#if __has_builtin(__builtin_amdgcn_cvt_pk_fp8_f32)
  v = __builtin_amdgcn_cvt_pk_fp8_f32(x, y, v, false);
  v = __builtin_amdgcn_cvt_pk_fp8_f32(z, w, v, true);
#else
  asm("v_cvt_pk_fp8_f32 %0, %1, %2" : "+v"(v) : "v"(x), "v"(y));
  asm("v_cvt_pk_fp8_f32 %0, %1, %2 op_sel:[0,0,1]" : "+v"(v) : "v"(z), "v"(w));
#endif
  return v;
}

// dbf3 layout (kg-major fp8 fragment blocks): block(b, kg, rt) = (b*8+kg)*64+rt,
// 512 BYTES each. Slot s (0..63) holds 8 fp8: row = rt*16 + (s&15),
// k = kg*32 + (s>>4)*8 + 0..7. A wave's fragment load is one coalesced 512B
// global_load_dwordx2 (lane l reads slot l). fp8 e4m3 Gram precision is ample:
// G only reaches the output through the d2<THR gate and kd<=1.7e-5 terms.

// ---- prep: 4096 blocks x 128 thr (2 waves), one 16-row tile per block.
//      Phase A: wave w loads rows w*8..w*8+7 (coalesced 1KB f32), exact-f32 sq,
//      cvt->fp8, granule-XOR-swizzled LDS write (2-way bank = free).
//      Phase B (after barrier): wave w emits kg w*4..w*4+3: swizzled
//      ds_read_b64 -> coalesced 512B fragment store.
//      XCD-matched: XCD k (= px&7) writes batches [8k,8k+8) = main's readers.
__global__ __launch_bounds__(128) void prep_kernel(const float* __restrict__ din,
                                                   unsigned char* __restrict__ dbf3,
                                                   float* __restrict__ sq,
                                                   int write_bf) {
  __shared__ unsigned char T[16][256];           // 4 KB fp8 tile
  const int px = (int)blockIdx.x;
  const int wid = (int)threadIdx.x >> 6;         // 0,1
  const int l = (int)threadIdx.x & 63;
  const int tb = (px & 7) * 512 + (px >> 3);     // tile task 0..4095
  const int b = tb >> 6, rt = tb & 63;
  const float4* src =
      reinterpret_cast<const float4*>(din + ((size_t)b * NS + rt * 16) * DD) + l;
  #pragma unroll
  for (int j = 0; j < 8; ++j) {
    const int ri = wid * 8 + j;                  // row within tile
    float4 v = src[ri * 64];                     // row stride 256 f = 64 float4
    float s = v.x * v.x + v.y * v.y + v.z * v.z + v.w * v.w;
    #pragma unroll
    for (int off = 32; off > 0; off >>= 1) s += __shfl_xor(s, off, 64);
    if (l == 0) sq[(size_t)b * NS + rt * 16 + ri] = s;
    if (write_bf) {
      // lane l holds 4B fp8-granule g=l of row ri; swizzled pos g^( (ri&15)<<2 )
      const unsigned int w4 = pk_fp8x4(v.x, v.y, v.z, v.w);
      const int gp = l ^ ((ri & 15) << 2);
      *reinterpret_cast<unsigned int*>(&T[ri][gp * 4]) = w4;
    }
  }
  if (!write_bf) return;
  __syncthreads();
  // Phase B: slot l of kg-block = row (l&15), granules gd = kg*8+(l>>4)*2,+1
  // (consecutive, low2 of XOR const are 0 -> b64 read ok), swizzle ^((l&15)<<2)
  unsigned char* dst = dbf3 + (((size_t)b * 8) * 64 + rt) * 512 + (size_t)l * 8;
  #pragma unroll
  for (int q = 0; q < 4; ++q) {
    const int kg = wid * 4 + q;
    const int gd = kg * 8 + (l >> 4) * 2;
    const int gp = gd ^ ((l & 15) << 2);
    const u64 frag = *reinterpret_cast<const u64*>(&T[l & 15][gp * 4]);
    *reinterpret_cast<u64*>(dst + (size_t)kg * 64 * 512) = frag;
  }
}

// ---- main: blocks [0,2304): barrier-free LDS-free fp8-MFMA Gram (one batch,
// one upper-tri tile; 4 waves x 64x64). Fragment loads hit the LOCAL XCD L2.
// Software prefetch distance 1. blocks [2304,2816): denom2/C partials.
template <int MODE>
__global__ __launch_bounds__(256, 2) void main_kernel(
    const float* __restrict__ dvec, const unsigned char* __restrict__ dbf3,
    const float* __restrict__ sq, const float* __restrict__ S,
    const float* __restrict__ W, float* __restrict__ npart,
    float* __restrict__ dpart, float* __restrict__ cpart) {
  const int tid = threadIdx.x;
  const int lane = tid & 63;
  const int wid = tid >> 6;
  const int orig = (int)blockIdx.x;

  if (orig >= NT * NB) {
    // ---- denomC partials: blk in [0,512), 256 thr x 2 float4 each ----
    const int blk = orig - NT * NB;
    const int base = blk * 256 + tid;
    float dsum = 0.f, csum = 0.f;
    #pragma unroll
    for (int rpt = 0; rpt < 2; ++rpt) {
      const int idx = base + rpt * 131072;
      float4 w = reinterpret_cast<const float4*>(W)[idx];
      float4 s4 = reinterpret_cast<const float4*>(S)[idx];
      const int e0 = idx << 2;
      const int r = e0 >> 10, c0 = e0 & 1023;
      float wv[4] = {w.x, w.y, w.z, w.w};
      float sv[4] = {s4.x, s4.y, s4.z, s4.w};
      #pragma unroll
      for (int i = 0; i < 4; ++i) {
        const bool dg = (c0 + i) == r;
        const float a = wv[i] - (dg ? 1.0f : 0.0f);
        dsum = fmaf(a, a, dsum);
        const float bq = dg ? (1.0f - sv[i]) : sv[i];
        csum = fmaf(wv[i] * bq, bq, csum);   // W binary: W^2 == W
      }
    }
    #pragma unroll
    for (int off = 32; off > 0; off >>= 1) {
      dsum += __shfl_xor(dsum, off, 64);
      csum += __shfl_xor(csum, off, 64);
    }
    __shared__ float redD[4], redC[4];
    if (lane == 0) { redD[wid] = dsum; redC[wid] = csum; }
    __syncthreads();
    if (tid == 0) {
      dpart[blk] = redD[0] + redD[1] + redD[2] + redD[3];
      cpart[blk] = redC[0] + redC[1] + redC[2] + redC[3];
    }
    return;
  }

  const int wr = wid >> 1;
  const int wc = wid & 1;
  // XCD-chunked bijective swizzle (2304 = 8 * 288): XCD k gets bids
  // [288k, 288k+288) -> b in [8k, 8k+8) (t-fast) = the batches its L2 holds.
  const int bid = (orig & 7) * (NT * NB / 8) + (orig >> 3);
  const int t = bid % NT;
  const int b = bid / NT;
  int u = t, ti = 0;
  while (u >= 8 - ti) { u -= 8 - ti; ++ti; }
  const int tj = ti + u;
  const int brow = ti * 128;
  const int bcol = tj * 128;

  const int rtA0 = ti * 8 + wr * 4;   // A row-tiles (16 rows each)
  const int rtB0 = tj * 8 + wc * 4;   // B row-tiles (Gram columns)

  f32x4 acc[4][4];
  #pragma unroll
  for (int m = 0; m < 4; ++m)
    #pragma unroll
    for (int n = 0; n < 4; ++n) acc[m][n] = f32x4{0.f, 0.f, 0.f, 0.f};

  if (MODE == 0) {
    const unsigned char* pa =
        dbf3 + (((size_t)b * 8) * 64 + rtA0) * 512 + (size_t)lane * 8;
    const unsigned char* pb =
        dbf3 + (((size_t)b * 8) * 64 + rtB0) * 512 + (size_t)lane * 8;
    u64 af[4], bf[4], nf[4];
    #pragma unroll
    for (int m = 0; m < 4; ++m)
      af[m] = *reinterpret_cast<const u64*>(pa + m * 512);
    #pragma unroll
    for (int n = 0; n < 4; ++n)
      bf[n] = *reinterpret_cast<const u64*>(pb + n * 512);
    #pragma unroll
    for (int kg = 0; kg < 8; ++kg) {
      if (kg < 7) {
        #pragma unroll
        for (int m = 0; m < 4; ++m)
          nf[m] = *reinterpret_cast<const u64*>(pa + 32768 + m * 512);
      }
      #pragma unroll
      for (int n = 0; n < 4; ++n) {
        #pragma unroll
        for (int m = 0; m < 4; ++m)
          acc[m][n] = __builtin_amdgcn_mfma_f32_16x16x32_fp8_fp8(
              (long)af[m], (long)bf[n], acc[m][n], 0, 0, 0);
        if (kg < 7)
          bf[n] = *reinterpret_cast<const u64*>(pb + 32768 + n * 512);  // bf[n] dead
      }
      if (kg < 7) {
        #pragma unroll
        for (int m = 0; m < 4; ++m) af[m] = nf[m];
        pa += 32768; pb += 32768;
      }
    }
  } else {
    const float* pbase = dvec + (size_t)b * NS * DD + (lane >> 4) * 8;
    #pragma unroll
    for (int kg = 0; kg < 8; ++kg) {
      bf16x8 af[4], bf[4];
      #pragma unroll
      for (int m = 0; m < 4; ++m) {
        const float* p = pbase + (size_t)((rtA0 + m) * 16 + (lane & 15)) * DD + kg * 32;
        float4 v0 = reinterpret_cast<const float4*>(p)[0];
        float4 v1 = reinterpret_cast<const float4*>(p)[1];
        af[m][0] = (short)f2bf(v0.x); af[m][1] = (short)f2bf(v0.y);
        af[m][2] = (short)f2bf(v0.z); af[m][3] = (short)f2bf(v0.w);
        af[m][4] = (short)f2bf(v1.x); af[m][5] = (short)f2bf(v1.y);
        af[m][6] = (short)f2bf(v1.z); af[m][7] = (short)f2bf(v1.w);
      }
      #pragma unroll
      for (int n = 0; n < 4; ++n) {
        const float* p = pbase + (size_t)((rtB0 + n) * 16 + (lane & 15)) * DD + kg * 32;
        float4 v0 = reinterpret_cast<const float4*>(p)[0];
        float4 v1 = reinterpret_cast<const float4*>(p)[1];
        bf[n][0] = (short)f2bf(v0.x); bf[n][1] = (short)f2bf(v0.y);
        bf[n][2] = (short)f2bf(v0.z); bf[n][3] = (short)f2bf(v0.w);
        bf[n][4] = (short)f2bf(v1.x); bf[n][5] = (short)f2bf(v1.y);
        bf[n][6] = (short)f2bf(v1.z); bf[n][7] = (short)f2bf(v1.w);
      }
      #pragma unroll
      for (int m = 0; m < 4; ++m)
        #pragma unroll
        for (int n = 0; n < 4; ++n)
          acc[m][n] = __builtin_amdgcn_mfma_f32_16x16x32_bf16(af[m], bf[n], acc[m][n], 0, 0, 0);
    }
  }

  // ---- epilogue, two-pass: branch-free d2 min scan; rare kd path under one
  // ballot. exp(-dist) is sub-f32-eps vs S once d2 > THR. ----
  const float* sqb = sq + (size_t)b * NS;
  const int hi = lane >> 4, lo = lane & 15;
  float sqc[4];
  #pragma unroll
  for (int n = 0; n < 4; ++n) sqc[n] = sqb[bcol + wc * 64 + n * 16 + lo];
  float dmin = 1e30f;
  #pragma unroll
  for (int m = 0; m < 4; ++m) {
    #pragma unroll
    for (int j = 0; j < 4; ++j) {
      const int r = brow + wr * 64 + m * 16 + hi * 4 + j;
      const float sqr = sqb[r];
      #pragma unroll
      for (int n = 0; n < 4; ++n) {
        const int c = bcol + wc * 64 + n * 16 + lo;
        const float d2 = fmaxf(sqr + sqc[n] - 2.0f * acc[m][n][j], 0.0f);
        dmin = fminf(dmin, (r < c) ? d2 : 1e30f);
      }
    }
  }
  float wsum = 0.f;
  if (__any(dmin < THR)) {
    // pair (r,c), r<c: kd^2*(W[r][c]+W[c][r]) - 2*kd*(W[r][c]S[r][c]+W[c][r]S[c][r])
    float lsum = 0.f;
    #pragma unroll
    for (int m = 0; m < 4; ++m) {
      #pragma unroll
      for (int j = 0; j < 4; ++j) {
        const int r = brow + wr * 64 + m * 16 + hi * 4 + j;
        const float sqr = sqb[r];
        #pragma unroll
        for (int n = 0; n < 4; ++n) {
          const int c = bcol + wc * 64 + n * 16 + lo;
          const float d2 = fmaxf(sqr + sqc[n] - 2.0f * acc[m][n][j], 0.0f);
          if ((r < c) && (d2 < THR)) {
            const float kd = __expf(-sqrtf(d2));
            const float wrc = W[(size_t)r * NS + c];
            const float wcr = W[(size_t)c * NS + r];
            const float src_ = S[(size_t)r * NS + c];
            const float scr = S[(size_t)c * NS + r];
            lsum = fmaf(kd, kd * (wrc + wcr) - 2.0f * fmaf(wrc, src_, wcr * scr), lsum);
          }
        }
      }
    }
    #pragma unroll
    for (int off = 32; off > 0; off >>= 1) lsum += __shfl_xor(lsum, off, 64);
    wsum = lsum;
  }
  // unconditional per-(block,wave) partial (poison-safe, no atomics)
  if (lane == 0) npart[(size_t)bid * 4 + wid] = wsum;
}

// ---- final: npart[b*144 .. +144) per batch; out = sum_b 2*sqrt(C+n_b)/sqrt(D) ----
__global__ void final_kernel(const float* __restrict__ npart,
                             const float* __restrict__ dpart,
                             const float* __restrict__ cpart,
                             float* __restrict__ out) {
  const int lane = threadIdx.x;
  float dsum = 0.f, csum = 0.f;
  #pragma unroll
  for (int j = 0; j < 8; ++j) {
    dsum += dpart[lane + 64 * j];
    csum += cpart[lane + 64 * j];
  }
  #pragma unroll
  for (int off = 32; off > 0; off >>= 1) {
    dsum += __shfl_xor(dsum, off, 64);
    csum += __shfl_xor(csum, off, 64);
  }
  // lane b: reduce its batch's 36 tiles x 4 waves = 144 contiguous floats
  float nb = 0.f;
  const f32x4* np = reinterpret_cast<const f32x4*>(npart + (size_t)lane * 144);
  #pragma unroll
  for (int j = 0; j < 36; ++j) {
    f32x4 v = np[j];
    nb += v[0] + v[1] + v[2] + v[3];
  }
  float v = 2.0f * sqrtf(csum + nb);
  #pragma unroll
  for (int off = 32; off > 0; off >>= 1) v += __shfl_xor(v, off, 64);
  if (lane == 0) out[0] = v / sqrtf(dsum);
}

extern "C" void kernel_launch(void* const* d_in, const int* in_sizes, int n_in,
                              void* d_out, int out_size, void* d_ws, size_t ws_size,
                              hipStream_t stream) {
  const float* dvec = (const float*)d_in[0];
  const float* S = (const float*)d_in[1];
  const float* W = (const float*)d_in[2];
  float* out = (float*)d_out;

  const size_t bf_bytes = (size_t)NB * NS * DD;                           // 16 MiB fp8
  const size_t sq_bytes = (size_t)NB * NS * sizeof(float);                // 256 KiB
  const size_t small_bytes = sq_bytes + (9216 + 512 + 512) * sizeof(float);
  const bool full = ws_size >= bf_bytes + small_bytes;

  unsigned char* dbf3;
  float* sqp;
  if (full) {
    dbf3 = (unsigned char*)d_ws;
    sqp = (float*)((char*)d_ws + bf_bytes);
  } else {
    dbf3 = nullptr;
    sqp = (float*)d_ws;
  }
  float* npart = sqp + (size_t)NB * NS;    // 9216 floats (2304 blocks x 4 waves)
  float* dpart = npart + 9216;             // 512
  float* cpart = dpart + 512;              // 512

  prep_kernel<<<4096, 128, 0, stream>>>(dvec, dbf3, sqp, full ? 1 : 0);
  if (full)
    main_kernel<0><<<NT * NB + 512, 256, 0, stream>>>(dvec, dbf3, sqp, S, W,
                                                      npart, dpart, cpart);
  else
    main_kernel<1><<<NT * NB + 512, 256, 0, stream>>>(dvec, dbf3, sqp, S, W,
                                                      npart, dpart, cpart);
  final_kernel<<<1, 64, 0, stream>>>(npart, dpart, cpart, out);
}

// Round 17
// 40.133 us; speedup vs baseline: 2.8672x; 1.0498x over previous
//
#include <hip/hip_runtime.h>
#include <hip/hip_bf16.h>

#define NB 64
#define NS 1024
#define DD 256
#define NT 36          // upper-triangular 8x8 tile count
#define THR 120.0f     // dist^2 below which exp(-dist) can matter

typedef __attribute__((ext_vector_type(4))) float f32x4;
typedef __attribute__((ext_vector_type(8))) short bf16x8;
typedef __attribute__((ext_vector_type(8))) int i32x8;
typedef __attribute__((ext_vector_type(4))) unsigned int u32x4;
typedef unsigned long long u64;

__device__ __forceinline__ unsigned short f2bf(float x) {
  union { float f; unsigned int u; } c; c.f = x;
  unsigned int r = c.u + 0x7fffu + ((c.u >> 16) & 1u);
  return (unsigned short)(r >> 16);
}

// pack 4 f32 -> 4 fp8 e4m3 bytes (hardware cvt)
__device__ __forceinline__ unsigned int pk_fp8x4(float x, float y, float z, float w) {
  unsigned int v = 0;
#if __has_builtin(__builtin_amdgcn_cvt_pk_fp8_f32)
  v = __builtin_amdgcn_cvt_pk_fp8_f32(x, y, v, false);
  v = __builtin_amdgcn_cvt_pk_fp8_f32(z, w, v, true);
#else
  asm("v_cvt_pk_fp8_f32 %0, %1, %2" : "+v"(v) : "v"(x), "v"(y));
  asm("v_cvt_pk_fp8_f32 %0, %1, %2 op_sel:[0,0,1]" : "+v"(v) : "v"(z), "v"(w));
#endif
  return v;
}

// dbf4 layout (kc-major fp8 fragment blocks for K=128 MX-MFMA):
// block(b, kc, rt) = (b*2 + kc)*64 + rt, 2048 BYTES each (kc = K-half 0/1).
// Slot l (0..63) holds 32 fp8: row = rt*16 + (l&15),
// k = kc*128 + (l>>4)*32 + 0..31 (contiguous) — exactly the A/B operand
// register layout of mfma_scale_f32_16x16x128_f8f6f4. A wave's fragment load
// is one coalesced 2KB read (i32x8 per lane). fp8 e4m3 Gram precision is
// ample: G reaches the output only through the d2<THR gate + kd<=1.7e-5 terms.

// ---- prep: 4096 blocks x 128 thr (2 waves), one 16-row tile per block.
//      Phase A: wave w loads rows w*8..w*8+7 (coalesced 1KB f32), exact-f32 sq,
//      cvt->fp8, granule-XOR-swizzled LDS write (gp = g ^ ((row&15)<<2)).
//      Phase B (after barrier): wave w emits K-half kc=w: two swizzled 16B
//      LDS reads per lane (XOR const low2=0 -> chunks stay contiguous) ->
//      32B/lane coalesced fragment store.
//      XCD-matched: XCD k (= px&7) writes batches [8k,8k+8) = main's readers.
__global__ __launch_bounds__(128) void prep_kernel(const float* __restrict__ din,
                                                   unsigned char* __restrict__ dbf4,
                                                   float* __restrict__ sq,
                                                   int write_bf) {
  __shared__ unsigned char T[16][256];           // 4 KB fp8 tile
  const int px = (int)blockIdx.x;
  const int wid = (int)threadIdx.x >> 6;         // 0,1
  const int l = (int)threadIdx.x & 63;
  const int tb = (px & 7) * 512 + (px >> 3);     // tile task 0..4095
  const int b = tb >> 6, rt = tb & 63;
  const float4* src =
      reinterpret_cast<const float4*>(din + ((size_t)b * NS + rt * 16) * DD) + l;
  #pragma unroll
  for (int j = 0; j < 8; ++j) {
    const int ri = wid * 8 + j;                  // row within tile
    float4 v = src[ri * 64];                     // row stride 256 f = 64 float4
    float s = v.x * v.x + v.y * v.y + v.z * v.z + v.w * v.w;
    #pragma unroll
    for (int off = 32; off > 0; off >>= 1) s += __shfl_xor(s, off, 64);
    if (l == 0) sq[(size_t)b * NS + rt * 16 + ri] = s;
    if (write_bf) {
      // lane l holds 4B fp8-granule g=l of row ri; swizzled pos g^((ri&15)<<2)
      const unsigned int w4 = pk_fp8x4(v.x, v.y, v.z, v.w);
      const int gp = l ^ ((ri & 15) << 2);
      *reinterpret_cast<unsigned int*>(&T[ri][gp * 4]) = w4;
    }
  }
  if (!write_bf) return;
  __syncthreads();
  // Phase B: wave wid emits kc = wid. Lane l: row (l&15), granules
  // g0 = kc*32 + (l>>4)*8 .. +7, swizzle ^((l&15)<<2) (low2 of const = 0 ->
  // two contiguous 16B chunks). 32B/lane contiguous store.
  const int kc = wid;
  const int row = l & 15, cxor = row << 2;
  const int g0 = kc * 32 + (l >> 4) * 8;
  const u32x4 lo = *reinterpret_cast<const u32x4*>(&T[row][((g0 + 0) ^ cxor) * 4]);
  const u32x4 hi = *reinterpret_cast<const u32x4*>(&T[row][((g0 + 4) ^ cxor) * 4]);
  unsigned char* dst =
      dbf4 + (((size_t)b * 2 + kc) * 64 + rt) * 2048 + (size_t)l * 32;
  *reinterpret_cast<u32x4*>(dst) = lo;
  *reinterpret_cast<u32x4*>(dst + 16) = hi;
}

// ---- main: blocks [0,2304): barrier-free LDS-free MX-fp8 MFMA Gram (one
// batch, one upper-tri tile; 4 waves x 64x64; 2 K-halves x 16 MFMA of
// 16x16x128, unit scales). Fragment loads hit the LOCAL XCD L2.
// blocks [2304,2816): denom2/C partials.
template <int MODE>
__global__ __launch_bounds__(256, 2) void main_kernel(
    const float* __restrict__ dvec, const unsigned char* __restrict__ dbf4,
    const float* __restrict__ sq, const float* __restrict__ S,
    const float* __restrict__ W, float* __restrict__ npart,
    float* __restrict__ dpart, float* __restrict__ cpart) {
  const int tid = threadIdx.x;
  const int lane = tid & 63;
  const int wid = tid >> 6;
  const int orig = (int)blockIdx.x;

  if (orig >= NT * NB) {
    // ---- denomC partials: blk in [0,512), 256 thr x 2 float4 each ----
    const int blk = orig - NT * NB;
    const int base = blk * 256 + tid;
    float dsum = 0.f, csum = 0.f;
    #pragma unroll
    for (int rpt = 0; rpt < 2; ++rpt) {
      const int idx = base + rpt * 131072;
      float4 w = reinterpret_cast<const float4*>(W)[idx];
      float4 s4 = reinterpret_cast<const float4*>(S)[idx];
      const int e0 = idx << 2;
      const int r = e0 >> 10, c0 = e0 & 1023;
      float wv[4] = {w.x, w.y, w.z, w.w};
      float sv[4] = {s4.x, s4.y, s4.z, s4.w};
      #pragma unroll
      for (int i = 0; i < 4; ++i) {
        const bool dg = (c0 + i) == r;
        const float a = wv[i] - (dg ? 1.0f : 0.0f);
        dsum = fmaf(a, a, dsum);
        const float bq = dg ? (1.0f - sv[i]) : sv[i];
        csum = fmaf(wv[i] * bq, bq, csum);   // W binary: W^2 == W
      }
    }
    #pragma unroll
    for (int off = 32; off > 0; off >>= 1) {
      dsum += __shfl_xor(dsum, off, 64);
      csum += __shfl_xor(csum, off, 64);
    }
    __shared__ float redD[4], redC[4];
    if (lane == 0) { redD[wid] = dsum; redC[wid] = csum; }
    __syncthreads();
    if (tid == 0) {
      dpart[blk] = redD[0] + redD[1] + redD[2] + redD[3];
      cpart[blk] = redC[0] + redC[1] + redC[2] + redC[3];
    }
    return;
  }

  const int wr = wid >> 1;
  const int wc = wid & 1;
  // XCD-chunked bijective swizzle (2304 = 8 * 288): XCD k gets bids
  // [288k, 288k+288) -> b in [8k, 8k+8) (t-fast) = the batches its L2 holds.
  const int bid = (orig & 7) * (NT * NB / 8) + (orig >> 3);
  const int t = bid % NT;
  const int b = bid / NT;
  int u = t, ti = 0;
  while (u >= 8 - ti) { u -= 8 - ti; ++ti; }
  const int tj = ti + u;
  const int brow = ti * 128;
  const int bcol = tj * 128;

  const int rtA0 = ti * 8 + wr * 4;   // A row-tiles (16 rows each)
  const int rtB0 = tj * 8 + wc * 4;   // B row-tiles (Gram columns)

  f32x4 acc[4][4];
  #pragma unroll
  for (int m = 0; m < 4; ++m)
    #pragma unroll
    for (int n = 0; n < 4; ++n) acc[m][n] = f32x4{0.f, 0.f, 0.f, 0.f};

  if (MODE == 0) {
    const unsigned char* pa =
        dbf4 + (((size_t)b * 2) * 64 + rtA0) * 2048 + (size_t)lane * 32;
    const unsigned char* pb =
        dbf4 + (((size_t)b * 2) * 64 + rtB0) * 2048 + (size_t)lane * 32;
    #pragma unroll
    for (int kc = 0; kc < 2; ++kc) {
      i32x8 av[4], bv[4];
      #pragma unroll
      for (int m = 0; m < 4; ++m)
        av[m] = *reinterpret_cast<const i32x8*>(pa + (size_t)kc * 131072 + m * 2048);
      #pragma unroll
      for (int n = 0; n < 4; ++n)
        bv[n] = *reinterpret_cast<const i32x8*>(pb + (size_t)kc * 131072 + n * 2048);
      #pragma unroll
      for (int m = 0; m < 4; ++m)
        #pragma unroll
        for (int n = 0; n < 4; ++n)
          // fmtA=fmtB=0 (fp8 e4m3); scales = 127 -> 2^0 = 1.0 (unit, exact)
          acc[m][n] = __builtin_amdgcn_mfma_scale_f32_16x16x128_f8f6f4(
              av[m], bv[n], acc[m][n], 0, 0, 0, 127, 0, 127);
    }
  } else {
    const float* pbase = dvec + (size_t)b * NS * DD + (lane >> 4) * 8;
    #pragma unroll
    for (int kg = 0; kg < 8; ++kg) {
      bf16x8 af[4], bf[4];
      #pragma unroll
      for (int m = 0; m < 4; ++m) {
        const float* p = pbase + (size_t)((rtA0 + m) * 16 + (lane & 15)) * DD + kg * 32;
        float4 v0 = reinterpret_cast<const float4*>(p)[0];
        float4 v1 = reinterpret_cast<const float4*>(p)[1];
        af[m][0] = (short)f2bf(v0.x); af[m][1] = (short)f2bf(v0.y);
        af[m][2] = (short)f2bf(v0.z); af[m][3] = (short)f2bf(v0.w);
        af[m][4] = (short)f2bf(v1.x); af[m][5] = (short)f2bf(v1.y);
        af[m][6] = (short)f2bf(v1.z); af[m][7] = (short)f2bf(v1.w);
      }
      #pragma unroll
      for (int n = 0; n < 4; ++n) {
        const float* p = pbase + (size_t)((rtB0 + n) * 16 + (lane & 15)) * DD + kg * 32;
        float4 v0 = reinterpret_cast<const float4*>(p)[0];
        float4 v1 = reinterpret_cast<const float4*>(p)[1];
        bf[n][0] = (short)f2bf(v0.x); bf[n][1] = (short)f2bf(v0.y);
        bf[n][2] = (short)f2bf(v0.z); bf[n][3] = (short)f2bf(v0.w);
        bf[n][4] = (short)f2bf(v1.x); bf[n][5] = (short)f2bf(v1.y);
        bf[n][6] = (short)f2bf(v1.z); bf[n][7] = (short)f2bf(v1.w);
      }
      #pragma unroll
      for (int m = 0; m < 4; ++m)
        #pragma unroll
        for (int n = 0; n < 4; ++n)
          acc[m][n] = __builtin_amdgcn_mfma_f32_16x16x32_bf16(af[m], bf[n], acc[m][n], 0, 0, 0);
    }
  }

  // ---- epilogue, two-pass: branch-free d2 min scan; rare kd path under one
  // ballot. exp(-dist) is sub-f32-eps vs S once d2 > THR. ----
  const float* sqb = sq + (size_t)b * NS;
  const int hi = lane >> 4, lo = lane & 15;
  float sqc[4];
  #pragma unroll
  for (int n = 0; n < 4; ++n) sqc[n] = sqb[bcol + wc * 64 + n * 16 + lo];
  float dmin = 1e30f;
  #pragma unroll
  for (int m = 0; m < 4; ++m) {
    #pragma unroll
    for (int j = 0; j < 4; ++j) {
      const int r = brow + wr * 64 + m * 16 + hi * 4 + j;
      const float sqr = sqb[r];
      #pragma unroll
      for (int n = 0; n < 4; ++n) {
        const int c = bcol + wc * 64 + n * 16 + lo;
        const float d2 = fmaxf(sqr + sqc[n] - 2.0f * acc[m][n][j], 0.0f);
        dmin = fminf(dmin, (r < c) ? d2 : 1e30f);
      }
    }
  }
  float wsum = 0.f;
  if (__any(dmin < THR)) {
    // pair (r,c), r<c: kd^2*(W[r][c]+W[c][r]) - 2*kd*(W[r][c]S[r][c]+W[c][r]S[c][r])
    float lsum = 0.f;
    #pragma unroll
    for (int m = 0; m < 4; ++m) {
      #pragma unroll
      for (int j = 0; j < 4; ++j) {
        const int r = brow + wr * 64 + m * 16 + hi * 4 + j;
        const float sqr = sqb[r];
        #pragma unroll
        for (int n = 0; n < 4; ++n) {
          const int c = bcol + wc * 64 + n * 16 + lo;
          const float d2 = fmaxf(sqr + sqc[n] - 2.0f * acc[m][n][j], 0.0f);
          if ((r < c) && (d2 < THR)) {
            const float kd = __expf(-sqrtf(d2));
            const float wrc = W[(size_t)r * NS + c];
            const float wcr = W[(size_t)c * NS + r];
            const float src_ = S[(size_t)r * NS + c];
            const float scr = S[(size_t)c * NS + r];
            lsum = fmaf(kd, kd * (wrc + wcr) - 2.0f * fmaf(wrc, src_, wcr * scr), lsum);
          }
        }
      }
    }
    #pragma unroll
    for (int off = 32; off > 0; off >>= 1) lsum += __shfl_xor(lsum, off, 64);
    wsum = lsum;
  }
  // unconditional per-(block,wave) partial (poison-safe, no atomics)
  if (lane == 0) npart[(size_t)bid * 4 + wid] = wsum;
}

// ---- final: npart[b*144 .. +144) per batch; out = sum_b 2*sqrt(C+n_b)/sqrt(D) ----
__global__ void final_kernel(const float* __restrict__ npart,
                             const float* __restrict__ dpart,
                             const float* __restrict__ cpart,
                             float* __restrict__ out) {
  const int lane = threadIdx.x;
  float dsum = 0.f, csum = 0.f;
  #pragma unroll
  for (int j = 0; j < 8; ++j) {
    dsum += dpart[lane + 64 * j];
    csum += cpart[lane + 64 * j];
  }
  #pragma unroll
  for (int off = 32; off > 0; off >>= 1) {
    dsum += __shfl_xor(dsum, off, 64);
    csum += __shfl_xor(csum, off, 64);
  }
  // lane b: reduce its batch's 36 tiles x 4 waves = 144 contiguous floats
  float nb = 0.f;
  const f32x4* np = reinterpret_cast<const f32x4*>(npart + (size_t)lane * 144);
  #pragma unroll
  for (int j = 0; j < 36; ++j) {
    f32x4 v = np[j];
    nb += v[0] + v[1] + v[2] + v[3];
  }
  float v = 2.0f * sqrtf(csum + nb);
  #pragma unroll
  for (int off = 32; off > 0; off >>= 1) v += __shfl_xor(v, off, 64);
  if (lane == 0) out[0] = v / sqrtf(dsum);
}

extern "C" void kernel_launch(void* const* d_in, const int* in_sizes, int n_in,
                              void* d_out, int out_size, void* d_ws, size_t ws_size,
                              hipStream_t stream) {
  const float* dvec = (const float*)d_in[0];
  const float* S = (const float*)d_in[1];
  const float* W = (const float*)d_in[2];
  float* out = (float*)d_out;

  const size_t bf_bytes = (size_t)NB * NS * DD;                           // 16 MiB fp8
  const size_t sq_bytes = (size_t)NB * NS * sizeof(float);                // 256 KiB
  const size_t small_bytes = sq_bytes + (9216 + 512 + 512) * sizeof(float);
  const bool full = ws_size >= bf_bytes + small_bytes;

  unsigned char* dbf4;
  float* sqp;
  if (full) {
    dbf4 = (unsigned char*)d_ws;
    sqp = (float*)((char*)d_ws + bf_bytes);
  } else {
    dbf4 = nullptr;
    sqp = (float*)d_ws;
  }
  float* npart = sqp + (size_t)NB * NS;    // 9216 floats (2304 blocks x 4 waves)
  float* dpart = npart + 9216;             // 512
  float* cpart = dpart + 512;              // 512

  prep_kernel<<<4096, 128, 0, stream>>>(dvec, dbf4, sqp, full ? 1 : 0);
  if (full)
    main_kernel<0><<<NT * NB + 512, 256, 0, stream>>>(dvec, dbf4, sqp, S, W,
                                                      npart, dpart, cpart);
  else
    main_kernel<1><<<NT * NB + 512, 256, 0, stream>>>(dvec, dbf4, sqp, S, W,
                                                      npart, dpart, cpart);
  final_kernel<<<1, 64, 0, stream>>>(npart, dpart, cpart, out);
}